// Round 19
// baseline (394.753 us; speedup 1.0000x reference)
//
#include <hip/hip_runtime.h>

typedef __attribute__((ext_vector_type(8)))  short s8b;      // 8 x bf16
typedef __attribute__((ext_vector_type(16))) float v16f;     // 32x32 f32 acc
typedef __attribute__((ext_vector_type(4)))  float v4f;
typedef __attribute__((ext_vector_type(4)))  unsigned int u32x4;
typedef __attribute__((ext_vector_type(4)))  int i32x4;      // 16 x i8 operand
typedef __attribute__((ext_vector_type(16))) int i32x16;     // 32x32 i32 acc
typedef unsigned short u16;
typedef unsigned char u8;
typedef unsigned int u32;

#define Q25_ONE (1 << 25)

__device__ __forceinline__ void split1(float f, u16 &h, u16 &l) {
  unsigned u = __builtin_bit_cast(unsigned, f);
  unsigned hu = u & 0xffff0000u;
  float lf = f - __builtin_bit_cast(float, hu);
  h = (u16)(u >> 16);
  l = (u16)(__builtin_bit_cast(unsigned, lf) >> 16);
}

__device__ __forceinline__ v16f mfma32bf(s8b a, s8b b, v16f c) {
  return __builtin_amdgcn_mfma_f32_32x32x16_bf16(a, b, c, 0, 0, 0);
}
__device__ __forceinline__ i32x16 mfma_i8_32(i32x4 a, i32x4 b, i32x16 c) {
  return __builtin_amdgcn_mfma_i32_32x32x32_i8(a, b, c, 0, 0, 0);
}
__device__ __forceinline__ i32x4 mfma_i8_16(i32x4 a, i32x4 b, i32x4 c) {
  return __builtin_amdgcn_mfma_i32_16x16x64_i8(a, b, c, 0, 0, 0);
}

// pack low bytes of 4 ints into one dword
__device__ __forceinline__ u32 pack4(int b0, int b1, int b2, int b3) {
  u32 t0 = __builtin_amdgcn_perm((u32)b1, (u32)b0, 0x0C0C0400u);
  u32 t1 = __builtin_amdgcn_perm((u32)b3, (u32)b2, 0x0C0C0400u);
  return __builtin_amdgcn_perm(t1, t0, 0x05040100u);
}

// ---------------- prep kernels ----------------------------------------------
__global__ void k_prep_w(const float* __restrict__ W2, const float* __restrict__ W3,
                         const float* __restrict__ W4, const float* __restrict__ W0,
                         signed char* __restrict__ w2q, signed char* __restrict__ w3q,
                         signed char* __restrict__ w0q,
                         u16* __restrict__ w4h, u16* __restrict__ w4l) {
  int i = blockIdx.x * 256 + threadIdx.x;
  if (i < 65536) {
    int q = (int)rintf(W2[i] * 2048.0f);
    q = min(max(q, -127), 127); w2q[i] = (signed char)q;
    q = (int)rintf(W3[i] * 2048.0f);
    q = min(max(q, -127), 127); w3q[i] = (signed char)q;
  }
  if (i < 4096) {                           // W0 padded [16][256]
    int n = i >> 8, k = i & 255;
    float v = (n < 10) ? W0[n * 256 + k] : 0.0f;
    int q = (int)rintf(v * 2048.0f);
    q = min(max(q, -127), 127); w0q[i] = (signed char)q;
  }
  if (i < 200704) {
    u16 h, lo;
    split1(W4[i], h, lo); w4h[i] = h; w4l[i] = lo;
  }
}

__global__ void k_prep_small(const float* __restrict__ W1, const float* __restrict__ b0,
                             signed char* __restrict__ w1q, float* __restrict__ b0p) {
  int i = blockIdx.x * 256 + threadIdx.x;
  if (i < 8192) {
    int n = i >> 5, k = i & 31;
    float v = (k < 10) ? W1[n * 10 + k] : 0.0f;
    int q = (int)rintf(v * 2048.0f);
    q = min(max(q, -127), 127); w1q[i] = (signed char)q;
  } else if (i < 8208) {
    int k = i - 8192;
    b0p[k] = (k < 10) ? b0[k] : 0.0f;
  }
}

// ---------------- drive = data @ W4^T + b4 (bf16 3-pass, once) ---------------
__device__ __forceinline__ void split_pack8(v4f x0, v4f x1, s8b &hi, s8b &lo) {
  float f[8];
  #pragma unroll
  for (int j = 0; j < 4; ++j) { f[j] = x0[j]; f[4 + j] = x1[j]; }
  u32x4 vh, vl;
  #pragma unroll
  for (int j = 0; j < 4; ++j) {
    unsigned u0 = __builtin_bit_cast(unsigned, f[2 * j]);
    unsigned u1 = __builtin_bit_cast(unsigned, f[2 * j + 1]);
    unsigned h0 = u0 & 0xffff0000u, h1 = u1 & 0xffff0000u;
    float l0 = f[2 * j]     - __builtin_bit_cast(float, h0);
    float l1 = f[2 * j + 1] - __builtin_bit_cast(float, h1);
    vh[j] = (u0 >> 16) | h1;
    vl[j] = (__builtin_bit_cast(unsigned, l0) >> 16) |
            (__builtin_bit_cast(unsigned, l1) & 0xffff0000u);
  }
  hi = __builtin_bit_cast(s8b, vh);
  lo = __builtin_bit_cast(s8b, vl);
}

__global__ void __launch_bounds__(256, 1) k_drive(
    const float* __restrict__ data, const u16* __restrict__ w4h,
    const u16* __restrict__ w4l, const float* __restrict__ b4,
    int* __restrict__ drive) {
  const int tid = threadIdx.x;
  const int w = tid >> 6, l = tid & 63;
  const int m = l & 31, g = l >> 5;
  const int rb = blockIdx.x * 64;
  const int nbase = w * 64;
  float b4v0 = b4[nbase + m], b4v1 = b4[nbase + 32 + m];
  v16f acc[2][2];
  #pragma unroll
  for (int r = 0; r < 16; ++r) {
    acc[0][0][r] = b4v0; acc[0][1][r] = b4v1;
    acc[1][0][r] = b4v0; acc[1][1][r] = b4v1;
  }
  for (int kt = 0; kt < 49; ++kt) {
    int k0 = kt * 16 + g * 8;
    s8b aH[2], aL[2], bH[2], bL[2];
    #pragma unroll
    for (int mt = 0; mt < 2; ++mt) {
      const float* p = data + (size_t)(rb + 32 * mt + m) * 784 + k0;
      v4f x0 = *(const v4f*)p;
      v4f x1 = *(const v4f*)(p + 4);
      split_pack8(x0, x1, aH[mt], aL[mt]);
    }
    #pragma unroll
    for (int nt = 0; nt < 2; ++nt) {
      int off = (nbase + 32 * nt + m) * 784 + k0;
      bH[nt] = *(const s8b*)(w4h + off);
      bL[nt] = *(const s8b*)(w4l + off);
    }
    #pragma unroll
    for (int mt = 0; mt < 2; ++mt)
      #pragma unroll
      for (int nt = 0; nt < 2; ++nt) {
        acc[mt][nt] = mfma32bf(aH[mt], bH[nt], acc[mt][nt]);
        acc[mt][nt] = mfma32bf(aL[mt], bH[nt], acc[mt][nt]);
        acc[mt][nt] = mfma32bf(aH[mt], bL[nt], acc[mt][nt]);
      }
  }
  #pragma unroll
  for (int mt = 0; mt < 2; ++mt)
    #pragma unroll
    for (int nt = 0; nt < 2; ++nt)
      #pragma unroll
      for (int r = 0; r < 16; ++r) {
        int row = rb + 32 * mt + (r & 3) + 8 * (r >> 2) + 4 * g;
        int col = nbase + 32 * nt + m;
        drive[(size_t)row * 256 + col] = (int)rintf(acc[mt][nt][r] * 33554432.0f);
      }
}

// ---------------- main persistent stepper ------------------------------------
// 256 blocks x 64 rows (1 block/CU, single round). Each wave: 32 output cols,
// TWO 32-row m-tiles. 4 big gemms into 8 AGPR accumulator sets before any
// epilogue (max ILP); drive streamed from L2; b2 Q25 in LDS (broadcast).
// Chunk-transposed state, swapped-operand MFMA, permlane-coalesced b128 writes.
__global__ void __launch_bounds__(512, 2) k_main(
    const float* __restrict__ s0g, const float* __restrict__ s1g,
    const float* __restrict__ s2g, const float* __restrict__ b2,
    const int* __restrict__ Tp,
    const signed char* __restrict__ w2q, const signed char* __restrict__ w3q,
    const signed char* __restrict__ w0q, const signed char* __restrict__ w1q,
    const float* __restrict__ b0p, const int* __restrict__ drive,
    float* __restrict__ out0, float* __restrict__ out1, float* __restrict__ out2) {
  extern __shared__ u8 sm8[];
  // state arrays: [16 chunks][64 rows][16B] = 16 KB each
  u8* s1hA = sm8;
  u8* s1lA = sm8 + 16384;
  u8* s2hA = sm8 + 32768;
  u8* s2lA = sm8 + 49152;
  u8* s1hB = sm8 + 65536;
  u8* s1lB = sm8 + 81920;
  u8* s2hB = sm8 + 98304;
  u8* s2lB = sm8 + 114688;
  u8* s0hA = sm8 + 131072;        // [64][48] i8, 3072 B each
  u8* s0lA = sm8 + 134144;
  u8* s0hB = sm8 + 137216;
  u8* s0lB = sm8 + 140288;
  u8* w0s  = sm8 + 143360;        // [16 chunks][16 rows][16B], 4 KB
  int* b2s = (int*)(sm8 + 147456);  // [256] Q25, 1 KB
  // total 148480 B

  const int tid = threadIdx.x;
  const int w = tid >> 6, l = tid & 63;
  const int m = l & 31, g = l >> 5;
  const int m16 = l & 15, g4 = l >> 4;
  const int rb = blockIdx.x * 64;

  // ---- stage weights into registers (A-operand fragments) ----
  i32x4 w2F[8], w3F[8], w1F;
  {
    const int wo = (w * 32 + m) * 256 + g * 16;
    #pragma unroll
    for (int kt = 0; kt < 8; ++kt) {
      w2F[kt] = *(const i32x4*)(w2q + wo + kt * 32);
      w3F[kt] = *(const i32x4*)(w3q + wo + kt * 32);
    }
    w1F = *(const i32x4*)(w1q + (w * 32 + m) * 32 + g * 16);
  }

  // ---- init LDS states (h/l split, chunk-transposed, 64 rows) ----
  for (int i = tid; i < 16384; i += 512) {
    int row = i >> 8, c = i & 255;
    int idx = ((c >> 4) << 10) + row * 16 + (c & 15);   // chunk*1024 + row*16
    int q = (int)rintf(s1g[(size_t)(rb + row) * 256 + c] * 16384.0f);
    int h = (q + 128) >> 8;
    s1hA[idx] = (u8)h; s1lA[idx] = (u8)(q - (h << 8));
    q = (int)rintf(s2g[(size_t)(rb + row) * 256 + c] * 16384.0f);
    h = (q + 128) >> 8;
    s2hA[idx] = (u8)h; s2lA[idx] = (u8)(q - (h << 8));
  }
  for (int i = tid; i < 3072; i += 512) {       // [64][48], pad zero
    int row = i / 48, c = i - row * 48;
    float v = (c < 10) ? s0g[(rb + row) * 10 + c] : 0.0f;
    int q = (int)rintf(v * 16384.0f);
    int h = (q + 128) >> 8;
    s0hA[i] = (u8)h; s0lA[i] = (u8)(q - (h << 8));
    s0hB[i] = 0; s0lB[i] = 0;
  }
  if (tid < 256) {                  // stage W0 chunk-transposed
    int r = tid >> 4, c = tid & 15;
    *(i32x4*)(w0s + c * 256 + r * 16) = *(const i32x4*)(w0q + r * 256 + c * 16);
    b2s[tid] = (int)rintf(b2[tid] * 33554432.0f);   // Q25
  }

  int b0r[4];
  if (w < 4) {
    #pragma unroll
    for (int e = 0; e < 4; ++e)
      b0r[e] = (int)rintf(b0p[4 * g4 + e] * 33554432.0f);
  }

  const int T = Tp[0];
  // bases
  const int rdB0t = m * 16 + g * 1024;                // tile0 gemm B-read
  const int rdB1t = (32 + m) * 16 + g * 1024;         // tile1 gemm B-read
  const int wcb0 = (w * 2 + g) * 1024 + m * 16;       // tile0 coalesced write
  const int wcb1 = (w * 2 + g) * 1024 + (32 + m) * 16;
  const int arow = ((w >> 1) & 1) * 32 + (w & 1) * 16 + m16;  // n0 row (w<4)
  const int rdN0 = arow * 16 + g4 * 1024;             // n0 B-read base
  const int* drv0 = drive + (size_t)(rb + m) * 256 + w * 32 + 4 * g;
  const int* drv1 = drive + (size_t)(rb + 32 + m) * 256 + w * 32 + 4 * g;
  const int* b2p = b2s + w * 32 + 4 * g;
  float* o1p0 = out1 + (size_t)(rb + m) * 256 + w * 32 + 4 * g;
  float* o1p1 = out1 + (size_t)(rb + 32 + m) * 256 + w * 32 + 4 * g;
  float* o2p0 = out2 + (size_t)(rb + m) * 256 + w * 32 + 4 * g;
  float* o2p1 = out2 + (size_t)(rb + 32 + m) * 256 + w * 32 + 4 * g;
  __syncthreads();

  u8 *s1ch = s1hA, *s1cl = s1lA, *s2ch = s2hA, *s2cl = s2lA;
  u8 *s1nh = s1hB, *s1nl = s1lB, *s2nh = s2hB, *s2nl = s2lB;
  u8 *s0ch = s0hA, *s0cl = s0lA, *s0nh = s0hB, *s0nl = s0lB;

  for (int t = 0; t < T; ++t) {
    const bool last = (t == T - 1);

    // ================= all 4 gemms first (8 AGPR acc sets) =================
    i32x16 h2a, c2a, h2b, c2b;    // n2 tile0 / tile1
    i32x16 h1a, c1a, h1b, c1b;    // n1 tile0 / tile1
    #pragma unroll
    for (int r = 0; r < 16; ++r) {
      h2a[r] = 0; c2a[r] = 0; h2b[r] = 0; c2b[r] = 0;
      h1a[r] = 0; c1a[r] = 0; h1b[r] = 0; c1b[r] = 0;
    }
    {   // s0 @ W1^T terms
      i32x4 B0h = *(const i32x4*)(s0ch + m * 48 + g * 16);
      i32x4 B0l = *(const i32x4*)(s0cl + m * 48 + g * 16);
      i32x4 B1h = *(const i32x4*)(s0ch + (32 + m) * 48 + g * 16);
      i32x4 B1l = *(const i32x4*)(s0cl + (32 + m) * 48 + g * 16);
      h1a = mfma_i8_32(w1F, B0h, h1a);
      c1a = mfma_i8_32(w1F, B0l, c1a);
      h1b = mfma_i8_32(w1F, B1h, h1b);
      c1b = mfma_i8_32(w1F, B1l, c1b);
    }
    #pragma unroll
    for (int kt = 0; kt < 8; ++kt) {
      // n2 reads s1
      i32x4 Bh0 = *(const i32x4*)(s1ch + rdB0t + kt * 2048);
      i32x4 Bl0 = *(const i32x4*)(s1cl + rdB0t + kt * 2048);
      i32x4 Bh1 = *(const i32x4*)(s1ch + rdB1t + kt * 2048);
      i32x4 Bl1 = *(const i32x4*)(s1cl + rdB1t + kt * 2048);
      h2a = mfma_i8_32(w3F[kt], Bh0, h2a);
      c2a = mfma_i8_32(w3F[kt], Bl0, c2a);
      h2b = mfma_i8_32(w3F[kt], Bh1, h2b);
      c2b = mfma_i8_32(w3F[kt], Bl1, c2b);
      // n1 reads s2
      i32x4 Ch0 = *(const i32x4*)(s2ch + rdB0t + kt * 2048);
      i32x4 Cl0 = *(const i32x4*)(s2cl + rdB0t + kt * 2048);
      i32x4 Ch1 = *(const i32x4*)(s2ch + rdB1t + kt * 2048);
      i32x4 Cl1 = *(const i32x4*)(s2cl + rdB1t + kt * 2048);
      h1a = mfma_i8_32(w2F[kt], Ch0, h1a);
      c1a = mfma_i8_32(w2F[kt], Cl0, c1a);
      h1b = mfma_i8_32(w2F[kt], Ch1, h1b);
      c1b = mfma_i8_32(w2F[kt], Cl1, c1b);
    }

    // ---- n0 = clamp(b0 + s1 @ W0^T), waves 0-3 ----
    u32 n0h = 0, n0l = 0;
    if (w < 4) {
      i32x4 ph, p1;
      ph.x = ph.y = ph.z = ph.w = 0;
      p1.x = p1.y = p1.z = p1.w = 0;
      #pragma unroll
      for (int kt = 0; kt < 4; ++kt) {
        i32x4 Bh = *(const i32x4*)(s1ch + rdN0 + kt * 4096);
        i32x4 Bl = *(const i32x4*)(s1cl + rdN0 + kt * 4096);
        i32x4 aw = *(const i32x4*)(w0s + m16 * 16 + g4 * 256 + kt * 1024);
        ph = mfma_i8_16(aw, Bh, ph);
        p1 = mfma_i8_16(aw, Bl, p1);
      }
      int hb[4], lb[4];
      #pragma unroll
      for (int e = 0; e < 4; ++e) {
        int pre = b0r[e] + (ph[e] << 8) + p1[e];
        int cl = min(max(pre, 0), Q25_ONE);
        int q14 = (cl + 1024) >> 11;
        int h = (cl + 263168) >> 19;
        hb[e] = h;
        lb[e] = q14 - (h << 8);
        if (last) {
          int n = 4 * g4 + e;
          if (n < 10) out0[(rb + arow) * 10 + n] = (float)cl * 0x1p-25f;
        }
      }
      n0h = pack4(hb[0], hb[1], hb[2], hb[3]);
      n0l = pack4(lb[0], lb[1], lb[2], lb[3]);
    }

    // ================= epilogues (reads all done) =================
    #define EPI(HH, CC, BIASJ, DSTH, DSTL, WCB, OUTP)                        \
    {                                                                        \
      u32 hq[4], lq[4];                                                      \
      _Pragma("unroll")                                                      \
      for (int j = 0; j < 4; ++j) {                                          \
        int hb[4], lb[4], cls[4];                                            \
        _Pragma("unroll")                                                    \
        for (int e = 0; e < 4; ++e) {                                        \
          int r = j * 4 + e;                                                 \
          int pre = (BIASJ)[j][e] + ((HH)[r] << 8) + (CC)[r];                \
          int cl = min(max(pre, 0), Q25_ONE);                                \
          cls[e] = cl;                                                       \
          int q14 = (cl + 1024) >> 11;                                       \
          int h = (cl + 263168) >> 19;                                       \
          hb[e] = h;                                                         \
          lb[e] = q14 - (h << 8);                                            \
        }                                                                    \
        hq[j] = pack4(hb[0], hb[1], hb[2], hb[3]);                           \
        lq[j] = pack4(lb[0], lb[1], lb[2], lb[3]);                           \
        if (last) {                                                          \
          v4f ov;                                                            \
          _Pragma("unroll")                                                  \
          for (int e = 0; e < 4; ++e) ov[e] = (float)cls[e] * 0x1p-25f;      \
          *(v4f*)((OUTP) + 8 * j) = ov;                                      \
        }                                                                    \
      }                                                                      \
      asm volatile("v_permlane32_swap_b32 %0, %1" : "+v"(hq[0]), "+v"(hq[2]));\
      asm volatile("v_permlane32_swap_b32 %0, %1" : "+v"(hq[1]), "+v"(hq[3]));\
      asm volatile("v_permlane32_swap_b32 %0, %1" : "+v"(lq[0]), "+v"(lq[2]));\
      asm volatile("v_permlane32_swap_b32 %0, %1" : "+v"(lq[1]), "+v"(lq[3]));\
      u32x4 v;                                                               \
      v[0] = hq[0]; v[1] = hq[2]; v[2] = hq[1]; v[3] = hq[3];                \
      *(u32x4*)((DSTH) + (WCB)) = v;                                         \
      v[0] = lq[0]; v[1] = lq[2]; v[2] = lq[1]; v[3] = lq[3];                \
      *(u32x4*)((DSTL) + (WCB)) = v;                                         \
    }

    {   // n2 tile0
      i32x4 bj[4];
      #pragma unroll
      for (int j = 0; j < 4; ++j) bj[j] = *(const i32x4*)(drv0 + 8 * j);
      EPI(h2a, c2a, bj, s2nh, s2nl, wcb0, o2p0)
    }
    {   // n2 tile1
      i32x4 bj[4];
      #pragma unroll
      for (int j = 0; j < 4; ++j) bj[j] = *(const i32x4*)(drv1 + 8 * j);
      EPI(h2b, c2b, bj, s2nh, s2nl, wcb1, o2p1)
    }
    {   // n1 tile0 (b2 from LDS, broadcast)
      i32x4 bj[4];
      #pragma unroll
      for (int j = 0; j < 4; ++j) bj[j] = *(const i32x4*)(b2p + 8 * j);
      EPI(h1a, c1a, bj, s1nh, s1nl, wcb0, o1p0)
      EPI(h1b, c1b, bj, s1nh, s1nl, wcb1, o1p1)
    }
    #undef EPI

    if (w < 4) {
      if (g4 < 2) {
        *(u32*)(s0nh + arow * 48 + 4 * g4) = n0h;
        *(u32*)(s0nl + arow * 48 + 4 * g4) = n0l;
      } else if (g4 == 2) {
        *(u16*)(s0nh + arow * 48 + 8) = (u16)(n0h & 0xffff);
        *(u16*)(s0nl + arow * 48 + 8) = (u16)(n0l & 0xffff);
      }
    }

    __syncthreads();   // next-state fully written; old fully read
    u8* tp;
    tp = s1ch; s1ch = s1nh; s1nh = tp;
    tp = s1cl; s1cl = s1nl; s1nl = tp;
    tp = s2ch; s2ch = s2nh; s2nh = tp;
    tp = s2cl; s2cl = s2nl; s2nl = tp;
    tp = s0ch; s0ch = s0nh; s0nh = tp;
    tp = s0cl; s0cl = s0nl; s0nl = tp;
  }
}

// ---------------- launcher ---------------------------------------------------
extern "C" void kernel_launch(void* const* d_in, const int* in_sizes, int n_in,
                              void* d_out, int out_size, void* d_ws, size_t ws_size,
                              hipStream_t stream) {
  const float* data = (const float*)d_in[0];
  const float* s0g  = (const float*)d_in[1];
  const float* s1g  = (const float*)d_in[2];
  const float* s2g  = (const float*)d_in[3];
  const float* W0   = (const float*)d_in[4];
  const float* b0   = (const float*)d_in[5];
  const float* W1   = (const float*)d_in[6];
  const float* W2   = (const float*)d_in[7];
  const float* b2   = (const float*)d_in[8];
  const float* W3   = (const float*)d_in[9];
  const float* W4   = (const float*)d_in[10];
  const float* b4   = (const float*)d_in[11];
  const int*   Tp   = (const int*)d_in[12];

  char* ws = (char*)d_ws;
  int* drive = (int*)ws;                                      // 16 MB, i32 Q25
  size_t off = 16777216;
  signed char* w2q = (signed char*)(ws + off); off += 65536;
  signed char* w3q = (signed char*)(ws + off); off += 65536;
  signed char* w0q = (signed char*)(ws + off); off += 4096;
  signed char* w1q = (signed char*)(ws + off); off += 8192;
  u16* w4h = (u16*)(ws + off); off += 401408;
  u16* w4l = (u16*)(ws + off); off += 401408;
  float* b0p = (float*)(ws + off); off += 64;

  float* out0 = (float*)d_out;
  float* out1 = out0 + 16384 * 10;
  float* out2 = out1 + 16384 * 256;

  hipFuncSetAttribute((const void*)k_main,
                      hipFuncAttributeMaxDynamicSharedMemorySize, 148480);

  k_prep_w<<<784, 256, 0, stream>>>(W2, W3, W4, W0, w2q, w3q, w0q, w4h, w4l);
  k_prep_small<<<33, 256, 0, stream>>>(W1, b0, w1q, b0p);
  k_drive<<<256, 256, 0, stream>>>(data, w4h, w4l, b4, drive);
  k_main<<<256, 512, 148480, stream>>>(s0g, s1g, s2g, b2, Tp,
      w2q, w3q, w0q, w1q, b0p, drive, out0, out1, out2);
}

// Round 20
// 279.306 us; speedup vs baseline: 1.4133x; 1.4133x over previous
//
#include <hip/hip_runtime.h>

typedef __attribute__((ext_vector_type(8)))  short s8b;      // 8 x bf16
typedef __attribute__((ext_vector_type(16))) float v16f;     // 32x32 f32 acc
typedef __attribute__((ext_vector_type(4)))  float v4f;
typedef __attribute__((ext_vector_type(4)))  unsigned int u32x4;
typedef __attribute__((ext_vector_type(4)))  int i32x4;      // 16 x i8 operand
typedef __attribute__((ext_vector_type(16))) int i32x16;     // 32x32 i32 acc
typedef unsigned short u16;
typedef unsigned char u8;
typedef unsigned int u32;

#define CQW (1.0f / 260096.0f)   // 1/(127*2048): stateQ7 x weightQ11 dequant

__device__ __forceinline__ float clamp01(float v) {
  return __builtin_fminf(__builtin_fmaxf(v, 0.0f), 1.0f);
}

__device__ __forceinline__ void split1(float f, u16 &h, u16 &l) {
  unsigned u = __builtin_bit_cast(unsigned, f);
  unsigned hu = u & 0xffff0000u;
  float lf = f - __builtin_bit_cast(float, hu);
  h = (u16)(u >> 16);
  l = (u16)(__builtin_bit_cast(unsigned, lf) >> 16);
}

__device__ __forceinline__ v16f mfma32bf(s8b a, s8b b, v16f c) {
  return __builtin_amdgcn_mfma_f32_32x32x16_bf16(a, b, c, 0, 0, 0);
}
__device__ __forceinline__ i32x16 mfma_i8_32(i32x4 a, i32x4 b, i32x16 c) {
  return __builtin_amdgcn_mfma_i32_32x32x32_i8(a, b, c, 0, 0, 0);
}
__device__ __forceinline__ i32x4 mfma_i8_16(i32x4 a, i32x4 b, i32x4 c) {
  return __builtin_amdgcn_mfma_i32_16x16x64_i8(a, b, c, 0, 0, 0);
}

// pack low bytes of 4 ints into one dword
__device__ __forceinline__ u32 pack4(int b0, int b1, int b2, int b3) {
  u32 t0 = __builtin_amdgcn_perm((u32)b1, (u32)b0, 0x0C0C0400u);
  u32 t1 = __builtin_amdgcn_perm((u32)b3, (u32)b2, 0x0C0C0400u);
  return __builtin_amdgcn_perm(t1, t0, 0x05040100u);
}

// ---------------- prep kernels ----------------------------------------------
__global__ void k_prep_w(const float* __restrict__ W2, const float* __restrict__ W3,
                         const float* __restrict__ W4, const float* __restrict__ W0,
                         signed char* __restrict__ w2q, signed char* __restrict__ w3q,
                         signed char* __restrict__ w0q,
                         u16* __restrict__ w4h, u16* __restrict__ w4l) {
  int i = blockIdx.x * 256 + threadIdx.x;
  if (i < 65536) {
    int q = (int)rintf(W2[i] * 2048.0f);
    q = min(max(q, -127), 127); w2q[i] = (signed char)q;
    q = (int)rintf(W3[i] * 2048.0f);
    q = min(max(q, -127), 127); w3q[i] = (signed char)q;
  }
  if (i < 4096) {                           // W0 padded [16][256]
    int n = i >> 8, k = i & 255;
    float v = (n < 10) ? W0[n * 256 + k] : 0.0f;
    int q = (int)rintf(v * 2048.0f);
    q = min(max(q, -127), 127); w0q[i] = (signed char)q;
  }
  if (i < 200704) {
    u16 h, lo;
    split1(W4[i], h, lo); w4h[i] = h; w4l[i] = lo;
  }
}

__global__ void k_prep_small(const float* __restrict__ W1, const float* __restrict__ b0,
                             signed char* __restrict__ w1q, float* __restrict__ b0p) {
  int i = blockIdx.x * 256 + threadIdx.x;
  if (i < 8192) {
    int n = i >> 5, k = i & 31;
    float v = (k < 10) ? W1[n * 10 + k] : 0.0f;
    int q = (int)rintf(v * 2048.0f);
    q = min(max(q, -127), 127); w1q[i] = (signed char)q;
  } else if (i < 8208) {
    int k = i - 8192;
    b0p[k] = (k < 10) ? b0[k] : 0.0f;
  }
}

// ---------------- drive = data @ W4^T + b4 (bf16 3-pass, once) ---------------
__device__ __forceinline__ void split_pack8(v4f x0, v4f x1, s8b &hi, s8b &lo) {
  float f[8];
  #pragma unroll
  for (int j = 0; j < 4; ++j) { f[j] = x0[j]; f[4 + j] = x1[j]; }
  u32x4 vh, vl;
  #pragma unroll
  for (int j = 0; j < 4; ++j) {
    unsigned u0 = __builtin_bit_cast(unsigned, f[2 * j]);
    unsigned u1 = __builtin_bit_cast(unsigned, f[2 * j + 1]);
    unsigned h0 = u0 & 0xffff0000u, h1 = u1 & 0xffff0000u;
    float l0 = f[2 * j]     - __builtin_bit_cast(float, h0);
    float l1 = f[2 * j + 1] - __builtin_bit_cast(float, h1);
    vh[j] = (u0 >> 16) | h1;
    vl[j] = (__builtin_bit_cast(unsigned, l0) >> 16) |
            (__builtin_bit_cast(unsigned, l1) & 0xffff0000u);
  }
  hi = __builtin_bit_cast(s8b, vh);
  lo = __builtin_bit_cast(s8b, vl);
}

__global__ void __launch_bounds__(256, 1) k_drive(
    const float* __restrict__ data, const u16* __restrict__ w4h,
    const u16* __restrict__ w4l, const float* __restrict__ b4,
    float* __restrict__ drive) {
  const int tid = threadIdx.x;
  const int w = tid >> 6, l = tid & 63;
  const int m = l & 31, g = l >> 5;
  const int rb = blockIdx.x * 64;
  const int nbase = w * 64;
  float b4v0 = b4[nbase + m], b4v1 = b4[nbase + 32 + m];
  v16f acc[2][2];
  #pragma unroll
  for (int r = 0; r < 16; ++r) {
    acc[0][0][r] = b4v0; acc[0][1][r] = b4v1;
    acc[1][0][r] = b4v0; acc[1][1][r] = b4v1;
  }
  for (int kt = 0; kt < 49; ++kt) {
    int k0 = kt * 16 + g * 8;
    s8b aH[2], aL[2], bH[2], bL[2];
    #pragma unroll
    for (int mt = 0; mt < 2; ++mt) {
      const float* p = data + (size_t)(rb + 32 * mt + m) * 784 + k0;
      v4f x0 = *(const v4f*)p;
      v4f x1 = *(const v4f*)(p + 4);
      split_pack8(x0, x1, aH[mt], aL[mt]);
    }
    #pragma unroll
    for (int nt = 0; nt < 2; ++nt) {
      int off = (nbase + 32 * nt + m) * 784 + k0;
      bH[nt] = *(const s8b*)(w4h + off);
      bL[nt] = *(const s8b*)(w4l + off);
    }
    #pragma unroll
    for (int mt = 0; mt < 2; ++mt)
      #pragma unroll
      for (int nt = 0; nt < 2; ++nt) {
        acc[mt][nt] = mfma32bf(aH[mt], bH[nt], acc[mt][nt]);
        acc[mt][nt] = mfma32bf(aL[mt], bH[nt], acc[mt][nt]);
        acc[mt][nt] = mfma32bf(aH[mt], bL[nt], acc[mt][nt]);
      }
  }
  #pragma unroll
  for (int mt = 0; mt < 2; ++mt)
    #pragma unroll
    for (int nt = 0; nt < 2; ++nt)
      #pragma unroll
      for (int r = 0; r < 16; ++r) {
        int row = rb + 32 * mt + (r & 3) + 8 * (r >> 2) + 4 * g;
        int col = nbase + 32 * nt + m;
        drive[(size_t)row * 256 + col] = acc[mt][nt][r];
      }
}

// ---------------- main persistent stepper ------------------------------------
// SINGLE-array Q7 i8 state (scale 127): half the MFMA / LDS reads / packing of
// the h/l Q14 scheme. Swapped-operand MFMA, chunk-transposed state, dbuf,
// 1 barrier/step, permlane-coalesced b128 write-back. Drive reloaded from L2
// per step (no __restrict__ so it cannot be hoisted into registers).
__global__ void __launch_bounds__(512, 2) k_main(
    const float* __restrict__ s0g, const float* __restrict__ s1g,
    const float* __restrict__ s2g, const float* __restrict__ b2,
    const int* __restrict__ Tp,
    const signed char* __restrict__ w2q, const signed char* __restrict__ w3q,
    const signed char* __restrict__ w0q, const signed char* __restrict__ w1q,
    const float* __restrict__ b0p, const float* drive,
    float* __restrict__ out0, float* __restrict__ out1, float* __restrict__ out2) {
  extern __shared__ u8 sm8[];
  u8* s1A = sm8;                  // [16 chunks][32 rows][16B] i8, 8 KB each
  u8* s1B = sm8 + 8192;
  u8* s2A = sm8 + 16384;
  u8* s2B = sm8 + 24576;
  u8* s0A = sm8 + 32768;          // [32][48] i8, 1536 B each
  u8* s0B = sm8 + 34304;
  u8* w0s = sm8 + 35840;          // [16 chunks][16 rows][16B], 4 KB
  float* b2s = (float*)(sm8 + 39936);   // [256] f32, 1 KB
  // total 40960 B

  const int tid = threadIdx.x;
  const int w = tid >> 6, l = tid & 63;
  const int m = l & 31, g = l >> 5;
  const int m16 = l & 15, g4 = l >> 4;
  const int rb = blockIdx.x * 32;

  // ---- stage weights into registers (A-operand fragments): 68 VGPR ----
  i32x4 w2F[8], w3F[8], w1F;
  {
    const int wo = (w * 32 + m) * 256 + g * 16;
    #pragma unroll
    for (int kt = 0; kt < 8; ++kt) {
      w2F[kt] = *(const i32x4*)(w2q + wo + kt * 32);
      w3F[kt] = *(const i32x4*)(w3q + wo + kt * 32);
    }
    w1F = *(const i32x4*)(w1q + (w * 32 + m) * 32 + g * 16);
  }

  // ---- init LDS states (Q7 single array, chunk-transposed) ----
  for (int i = tid; i < 8192; i += 512) {
    int row = i >> 8, c = i & 255;
    int idx = ((c >> 4) << 9) + row * 16 + (c & 15);
    s1A[idx] = (u8)(int)rintf(s1g[(size_t)(rb + row) * 256 + c] * 127.0f);
    s2A[idx] = (u8)(int)rintf(s2g[(size_t)(rb + row) * 256 + c] * 127.0f);
  }
  for (int i = tid; i < 1536; i += 512) {       // [32][48], pad zero
    int row = i / 48, c = i - row * 48;
    float v = (c < 10) ? s0g[(rb + row) * 10 + c] : 0.0f;
    s0A[i] = (u8)(int)rintf(v * 127.0f);
    s0B[i] = 0;
  }
  if (tid < 256) {                  // stage W0 chunk-transposed + b2
    int r = tid >> 4, c = tid & 15;
    *(i32x4*)(w0s + c * 256 + r * 16) = *(const i32x4*)(w0q + r * 256 + c * 16);
    b2s[tid] = b2[tid];
  }

  float b0r[4];
  if (w < 2) {
    #pragma unroll
    for (int e = 0; e < 4; ++e) b0r[e] = b0p[4 * g4 + e];
  }

  const int T = Tp[0];
  const int rdB = m * 16 + g * 512;             // gemm B-read base
  const int wcb = (w * 2 + g) * 512 + m * 16;   // coalesced b128 write base
  const int rdB0 = (16 * w + m16) * 16 + g4 * 512;
  const float* drv0 = drive + (size_t)(rb + m) * 256 + w * 32 + 4 * g;
  const float* b2p = b2s + w * 32 + 4 * g;
  __syncthreads();

  u8 *s1c = s1A, *s1n = s1B, *s2c = s2A, *s2n = s2B;
  u8 *s0c = s0A, *s0n = s0B;

  for (int t = 0; t < T; ++t) {
    const bool last = (t == T - 1);
    i32x16 acc;

    // ---- n2 = clamp(drive + s1 @ W3^T) ----
    #pragma unroll
    for (int r = 0; r < 16; ++r) acc[r] = 0;
    {
      const u8* bp = s1c + rdB;
      #pragma unroll
      for (int kt = 0; kt < 8; ++kt) {
        i32x4 B = *(const i32x4*)(bp + kt * 1024);
        acc = mfma_i8_32(w3F[kt], B, acc);
      }
    }
    u32 q2[4];
    #pragma unroll
    for (int j = 0; j < 4; ++j) {
      v4f dv = *(const v4f*)(drv0 + 8 * j);   // L2-resident, reloaded per step
      int qb[4];
      float vs[4];
      #pragma unroll
      for (int e = 0; e < 4; ++e) {
        float v = clamp01(__builtin_fmaf((float)acc[j * 4 + e], CQW, dv[e]));
        vs[e] = v;
        qb[e] = (int)rintf(v * 127.0f);
      }
      q2[j] = pack4(qb[0], qb[1], qb[2], qb[3]);
      if (last) {
        v4f ov; ov[0] = vs[0]; ov[1] = vs[1]; ov[2] = vs[2]; ov[3] = vs[3];
        *(v4f*)(out2 + (size_t)(rb + m) * 256 + w * 32 + 4 * g + 8 * j) = ov;
      }
    }

    // ---- n1 = clamp(b2 + s0 @ W1^T + s2 @ W2^T) ----
    #pragma unroll
    for (int r = 0; r < 16; ++r) acc[r] = 0;
    {
      i32x4 B0 = *(const i32x4*)(s0c + m * 48 + g * 16);
      acc = mfma_i8_32(w1F, B0, acc);
      const u8* bp = s2c + rdB;
      #pragma unroll
      for (int kt = 0; kt < 8; ++kt) {
        i32x4 B = *(const i32x4*)(bp + kt * 1024);
        acc = mfma_i8_32(w2F[kt], B, acc);
      }
    }
    u32 q1[4];
    #pragma unroll
    for (int j = 0; j < 4; ++j) {
      v4f bv = *(const v4f*)(b2p + 8 * j);
      int qb[4];
      float vs[4];
      #pragma unroll
      for (int e = 0; e < 4; ++e) {
        float v = clamp01(__builtin_fmaf((float)acc[j * 4 + e], CQW, bv[e]));
        vs[e] = v;
        qb[e] = (int)rintf(v * 127.0f);
      }
      q1[j] = pack4(qb[0], qb[1], qb[2], qb[3]);
      if (last) {
        v4f ov; ov[0] = vs[0]; ov[1] = vs[1]; ov[2] = vs[2]; ov[3] = vs[3];
        *(v4f*)(out1 + (size_t)(rb + m) * 256 + w * 32 + 4 * g + 8 * j) = ov;
      }
    }

    // ---- n0 = clamp(b0 + s1 @ W0^T), waves 0-1, 16x16x64 swapped ----
    u32 n0q = 0;
    if (w < 2) {
      i32x4 ph;
      ph.x = ph.y = ph.z = ph.w = 0;
      #pragma unroll
      for (int kt = 0; kt < 4; ++kt) {
        i32x4 B = *(const i32x4*)(s1c + rdB0 + kt * 2048);
        i32x4 aw = *(const i32x4*)(w0s + m16 * 16 + g4 * 256 + kt * 1024);
        ph = mfma_i8_16(aw, B, ph);
      }
      int qb[4];
      #pragma unroll
      for (int e = 0; e < 4; ++e) {
        float v = clamp01(__builtin_fmaf((float)ph[e], CQW, b0r[e]));
        qb[e] = (int)rintf(v * 127.0f);
        if (last) {
          int n = 4 * g4 + e;
          if (n < 10) out0[(rb + 16 * w + m16) * 10 + n] = v;
        }
      }
      n0q = pack4(qb[0], qb[1], qb[2], qb[3]);
    }

    // ---- coalesce via permlane32_swap and write one b128 per state ----
    asm volatile("v_permlane32_swap_b32 %0, %1" : "+v"(q2[0]), "+v"(q2[2]));
    asm volatile("v_permlane32_swap_b32 %0, %1" : "+v"(q2[1]), "+v"(q2[3]));
    asm volatile("v_permlane32_swap_b32 %0, %1" : "+v"(q1[0]), "+v"(q1[2]));
    asm volatile("v_permlane32_swap_b32 %0, %1" : "+v"(q1[1]), "+v"(q1[3]));
    {
      u32x4 v;
      v[0] = q2[0]; v[1] = q2[2]; v[2] = q2[1]; v[3] = q2[3];
      *(u32x4*)(s2n + wcb) = v;
      v[0] = q1[0]; v[1] = q1[2]; v[2] = q1[1]; v[3] = q1[3];
      *(u32x4*)(s1n + wcb) = v;
    }
    if (w < 2) {
      const int arow = 16 * w + m16;
      if (g4 < 2) {
        *(u32*)(s0n + arow * 48 + 4 * g4) = n0q;
      } else if (g4 == 2) {
        *(u16*)(s0n + arow * 48 + 8) = (u16)(n0q & 0xffff);
      }
    }

    __syncthreads();   // next-state fully written; old fully read
    u8* tp;
    tp = s1c; s1c = s1n; s1n = tp;
    tp = s2c; s2c = s2n; s2n = tp;
    tp = s0c; s0c = s0n; s0n = tp;
  }
}

// ---------------- launcher ---------------------------------------------------
extern "C" void kernel_launch(void* const* d_in, const int* in_sizes, int n_in,
                              void* d_out, int out_size, void* d_ws, size_t ws_size,
                              hipStream_t stream) {
  const float* data = (const float*)d_in[0];
  const float* s0g  = (const float*)d_in[1];
  const float* s1g  = (const float*)d_in[2];
  const float* s2g  = (const float*)d_in[3];
  const float* W0   = (const float*)d_in[4];
  const float* b0   = (const float*)d_in[5];
  const float* W1   = (const float*)d_in[6];
  const float* W2   = (const float*)d_in[7];
  const float* b2   = (const float*)d_in[8];
  const float* W3   = (const float*)d_in[9];
  const float* W4   = (const float*)d_in[10];
  const float* b4   = (const float*)d_in[11];
  const int*   Tp   = (const int*)d_in[12];

  char* ws = (char*)d_ws;
  float* drive = (float*)ws;                                  // 16 MB, f32
  size_t off = 16777216;
  signed char* w2q = (signed char*)(ws + off); off += 65536;
  signed char* w3q = (signed char*)(ws + off); off += 65536;
  signed char* w0q = (signed char*)(ws + off); off += 4096;
  signed char* w1q = (signed char*)(ws + off); off += 8192;
  u16* w4h = (u16*)(ws + off); off += 401408;
  u16* w4l = (u16*)(ws + off); off += 401408;
  float* b0p = (float*)(ws + off); off += 64;

  float* out0 = (float*)d_out;
  float* out1 = out0 + 16384 * 10;
  float* out2 = out1 + 16384 * 256;

  hipFuncSetAttribute((const void*)k_main,
                      hipFuncAttributeMaxDynamicSharedMemorySize, 40960);

  k_prep_w<<<784, 256, 0, stream>>>(W2, W3, W4, W0, w2q, w3q, w0q, w4h, w4l);
  k_prep_small<<<33, 256, 0, stream>>>(W1, b0, w1q, b0p);
  k_drive<<<256, 256, 0, stream>>>(data, w4h, w4l, b4, drive);
  k_main<<<512, 512, 40960, stream>>>(s0g, s1g, s2g, b2, Tp,
      w2q, w3q, w0q, w1q, b0p, drive, out0, out1, out2);
}